// Round 4
// baseline (658.954 us; speedup 1.0000x reference)
//
#include <hip/hip_runtime.h>

#define NCLS 5
#define NQRY 75
#define NTOT 80            // N = 80
#define FD   640
#define HIDN 4096
#define DNIN 465
#define KPAD 512           // DNIN padded to 512 for MFMA K
#define NPAD 512           // DNIN padded for GEMM3 N
#define LRDNI 1e-3f

#define KS1 8              // K-splits layer1 (K=512  -> 2 ksteps)
#define KS2 16             // K-splits layer2 (K=4096 -> 8 ksteps)
#define KS3 32             // K-splits layer3 (K=4096 -> 4 ksteps)

typedef short  v8s __attribute__((ext_vector_type(8)));
typedef float  v4f __attribute__((ext_vector_type(4)));

__device__ __forceinline__ ushort f2bf(float x) {
    uint u = __float_as_uint(x);
    u = (u + 0x7FFFu + ((u >> 16) & 1u)) >> 16;
    return (ushort)u;
}
__device__ __forceinline__ uint pk2(float a, float b) {
    return (uint)f2bf(a) | ((uint)f2bf(b) << 16);
}

// ---------------- init: supp = mean(feat_support, axis=1); qbuf = feat_query ----
__global__ void k_init(const float* __restrict__ fs, const float* __restrict__ fq,
                       float* __restrict__ supp, float* __restrict__ qbuf) {
    int idx = blockIdx.x * 256 + threadIdx.x;
    if (idx < NCLS * FD) {
        int c = idx / FD, d = idx % FD;
        float s = 0.f;
        #pragma unroll
        for (int t = 0; t < 5; t++) s += fs[(c * 5 + t) * FD + d];
        supp[idx] = s * 0.2f;
    }
    if (idx < NQRY * FD) qbuf[idx] = fq[idx];
}

// ---------------- weight converts (once per launch) ----------------
// W1 [4096,465] fp32 -> [4096,512] bf16 zero-padded K
__global__ void k_cvtW1(const float* __restrict__ W, ushort* __restrict__ Wb) {
    int idx = blockIdx.x * 256 + threadIdx.x;      // 4096*512
    int r = idx >> 9, c = idx & 511;
    Wb[idx] = (c < DNIN) ? f2bf(W[r * DNIN + c]) : (ushort)0;
}
// W3 [465,4096] fp32 -> [512,4096] bf16 zero-padded rows
__global__ void k_cvtW3(const float* __restrict__ W, ushort* __restrict__ Wb) {
    int idx = blockIdx.x * 256 + threadIdx.x;      // 512*4096
    int r = idx >> 12;
    Wb[idx] = (r < DNIN) ? f2bf(W[idx]) : (ushort)0;
}
// W2 [4096,4096] fp32 -> bf16 (vectorized x4)
__global__ void k_cvtW2(const float* __restrict__ W, ushort* __restrict__ Wb) {
    int idx = blockIdx.x * 256 + threadIdx.x;      // 4096*4096/4
    float4 v = ((const float4*)W)[idx];
    uint2 q; q.x = pk2(v.x, v.y); q.y = pk2(v.z, v.w);
    ((uint2*)Wb)[idx] = q;
}

__device__ __forceinline__ const float* rowptr(const float* supp, const float* qbuf, int r) {
    return (r < NCLS) ? (supp + r * FD) : (qbuf + (r - NCLS) * FD);
}

// ---- fused: norms + S = fn@fn^T + f (normalized) + stable rank -> perm --------
// FIN variant: only writes out[j*5+i] = S[i][5+j]*scale  (grid = 5 blocks)
template<bool FIN>
__global__ void k_simrank(const float* __restrict__ supp, const float* __restrict__ qbuf,
                          float* __restrict__ f, float* __restrict__ nrm,
                          float* __restrict__ S, int* __restrict__ perm,
                          const float* __restrict__ scale, float* __restrict__ out) {
    __shared__ float fi[FD];
    __shared__ float row[NTOT];
    __shared__ float ssh[NTOT];
    int i = blockIdx.x;
    int t = threadIdx.x;                // 128
    const float* ri = rowptr(supp, qbuf, i);
    for (int u = t; u < FD; u += 128) fi[u] = ri[u];
    __syncthreads();
    float dot = 0.f;
    if (t < NTOT) {
        const float* rj = rowptr(supp, qbuf, t);
        float ss = 0.f;
        for (int k = 0; k < FD; k += 4) {
            float4 a = *(const float4*)(fi + k);
            float4 b = *(const float4*)(rj + k);
            dot += a.x * b.x + a.y * b.y + a.z * b.z + a.w * b.w;
            ss  += b.x * b.x + b.y * b.y + b.z * b.z + b.w * b.w;
        }
        ssh[t] = ss;
    }
    __syncthreads();
    float ni = fmaxf(sqrtf(ssh[i]), 1e-12f);
    float inv_i = 1.0f / ni;
    if (t < NTOT) {
        float nt = fmaxf(sqrtf(ssh[t]), 1e-12f);
        float val = dot * inv_i / nt;
        if (FIN) {
            if (t >= NCLS) out[(t - NCLS) * NCLS + i] = val * scale[0];
        } else {
            row[t] = val;
            S[i * NTOT + t] = val;
        }
    }
    if (FIN) return;
    __syncthreads();
    for (int u = t; u < FD; u += 128) f[i * FD + u] = fi[u] * inv_i;
    if (t == 0) { nrm[i] = ni; perm[i * 81] = i; }
    if (t < NCLS) {
        float v = row[t]; int rank = 0;
        for (int k = 0; k < NCLS; k++) {
            float w = row[k];
            if (w > v || (w == v && k < t)) rank++;
        }
        perm[i * 81 + 1 + rank] = t;
    } else if (t < NTOT) {
        int j = t - NCLS; float v = row[t]; int rank = 0;
        for (int k = NCLS; k < NTOT; k++) {
            float w = row[k];
            if (w > v || (w == v && (k - NCLS) < j)) rank++;
        }
        perm[i * 81 + 6 + rank] = t;
    }
}

// m -> (a,b): masked entries of 81x81, row-major; a in 0..5, b in a+1..80
__device__ __forceinline__ void mask_ab(int m, int& a, int& b) {
    int start = 0, len = 80, aa = 0;
    while (m >= start + len) { start += len; len--; aa++; }
    a = aa; b = aa + 1 + (m - start);
}

// ---------------- gather Xb[i][m] = bf16(S[p[a]][p[b]]) + zero Gs ----------------
__global__ void k_gather(const float* __restrict__ S, const int* __restrict__ perm,
                         ushort* __restrict__ Xb, float* __restrict__ Gs) {
    __shared__ int p[81];
    int i = blockIdx.x;
    int t = threadIdx.x;                // 512
    if (t < 81) p[t] = perm[i * 81 + t];
    if (t < NTOT) Gs[i * NTOT + t] = 0.f;
    __syncthreads();
    if (t < DNIN) {
        int a, b; mask_ab(t, a, b);
        Xb[i * KPAD + t] = f2bf(S[p[a] * NTOT + p[b]]);
    } else if (t < KPAD) {
        Xb[i * KPAD + t] = 0;
    }
}

// ------- barrier-free direct-global MFMA GEMM partials --------------------------
// P[ks][80][ldc] = A[80,K] @ B[N,K]^T  restricted to this block's K-split.
// Fragments loaded straight from global in MFMA layout (row=l16, k=quad*8+j);
// no LDS, no __syncthreads -> loads pipeline freely across unrolled k-steps.
// NT = 16-col tiles per wave (block = 4 waves side by side).
template<int NT, int KSTEPS>
__global__ __launch_bounds__(256) void k_gemm(
        const ushort* __restrict__ A, int lda,
        const ushort* __restrict__ B, int ldb,
        float* __restrict__ C, int ldc) {
    int tid = threadIdx.x;
    int w = tid >> 6, lane = tid & 63, l16 = lane & 15, quad = lane >> 4;
    int n0 = blockIdx.x * (NT * 64) + w * NT * 16;
    int kc0 = blockIdx.y * (KSTEPS * 32);
    const ushort* Ap = A + l16 * lda + kc0 + quad * 8;
    const ushort* Bp = B + (size_t)(n0 + l16) * ldb + kc0 + quad * 8;

    v4f acc[5][NT];
    #pragma unroll
    for (int mt = 0; mt < 5; mt++)
        #pragma unroll
        for (int nt = 0; nt < NT; nt++) acc[mt][nt] = (v4f){0.f, 0.f, 0.f, 0.f};

    #pragma unroll
    for (int s = 0; s < KSTEPS; s++) {
        int ko = s * 32;
        v8s a[5], b[NT];
        #pragma unroll
        for (int mt = 0; mt < 5; mt++)
            a[mt] = *(const v8s*)(Ap + mt * 16 * lda + ko);
        #pragma unroll
        for (int nt = 0; nt < NT; nt++)
            b[nt] = *(const v8s*)(Bp + nt * 16 * ldb + ko);
        #pragma unroll
        for (int mt = 0; mt < 5; mt++)
            #pragma unroll
            for (int nt = 0; nt < NT; nt++)
                acc[mt][nt] = __builtin_amdgcn_mfma_f32_16x16x32_bf16(a[mt], b[nt], acc[mt][nt], 0, 0, 0);
    }
    // write fp32 partials: row = mt*16 + quad*4 + r ; col = n0 + nt*16 + l16
    float* Cp = C + (size_t)blockIdx.y * 80 * ldc;
    #pragma unroll
    for (int nt = 0; nt < NT; nt++) {
        int col = n0 + nt * 16 + l16;
        #pragma unroll
        for (int mt = 0; mt < 5; mt++)
            #pragma unroll
            for (int r = 0; r < 4; r++)
                Cp[(mt * 16 + quad * 4 + r) * ldc + col] = acc[mt][nt][r];
    }
}

// ---------------- H = bf16(relu(sum_ks P + bias))  (80 x 4096, x4 vectorized) ----
template<int NS>
__global__ void k_ep(const float* __restrict__ P, const float* __restrict__ bias,
                     ushort* __restrict__ H) {
    int idx = blockIdx.x * 256 + threadIdx.x;      // 80*4096/4
    float4 s = ((const float4*)bias)[idx & 1023];
    #pragma unroll
    for (int ks = 0; ks < NS; ks++) {
        float4 p = ((const float4*)P)[ks * (80 * HIDN / 4) + idx];
        s.x += p.x; s.y += p.y; s.z += p.z; s.w += p.w;
    }
    uint2 q;
    q.x = pk2(fmaxf(s.x, 0.f), fmaxf(s.y, 0.f));
    q.y = pk2(fmaxf(s.z, 0.f), fmaxf(s.w, 0.f));
    ((uint2*)H)[idx] = q;
}

// ---------------- scatter-add VJP of the gather (sums P3 partials + b3) --------
__global__ void k_scatter(const float* __restrict__ P3, const float* __restrict__ b3,
                          const int* __restrict__ perm, float* __restrict__ Gs) {
    __shared__ int p[81];
    int i = blockIdx.x;
    int t = threadIdx.x;                // 512
    if (t < 81) p[t] = perm[i * 81 + t];
    __syncthreads();
    if (t < DNIN) {
        float g = b3[t];
        #pragma unroll
        for (int ks = 0; ks < KS3; ks++) g += P3[ks * (80 * NPAD) + i * NPAD + t];
        int a, b; mask_ab(t, a, b);
        atomicAdd(&Gs[p[a] * NTOT + p[b]], g);
    }
}

// ---- dfeat = (Gs+Gs^T) @ f ; dx = (dfeat - (dfeat.f) f)/n ; target -= LR*dx ----
__global__ void k_bwd(const float* __restrict__ Gs, const float* __restrict__ f,
                      const float* __restrict__ nrm, float* __restrict__ target,
                      int row0) {
    int r = row0 + blockIdx.x;
    __shared__ float cj[NTOT];
    __shared__ float red[2];
    int t = threadIdx.x;                // 128 threads, 5 elems each
    if (t < NTOT) cj[t] = Gs[r * NTOT + t] + Gs[t * NTOT + r];
    __syncthreads();
    float df[5] = {0.f, 0.f, 0.f, 0.f, 0.f};
    for (int j = 0; j < NTOT; j++) {
        float c = cj[j];
        const float* fj = f + j * FD;
        #pragma unroll
        for (int u = 0; u < 5; u++) df[u] += c * fj[t + 128 * u];
    }
    const float* fr = f + r * FD;
    float frv[5]; float partial = 0.f;
    #pragma unroll
    for (int u = 0; u < 5; u++) { frv[u] = fr[t + 128 * u]; partial += df[u] * frv[u]; }
    #pragma unroll
    for (int o = 32; o > 0; o >>= 1) partial += __shfl_xor(partial, o, 64);
    if ((t & 63) == 0) red[t >> 6] = partial;
    __syncthreads();
    float dot = red[0] + red[1];
    float invn = 1.0f / nrm[r];
    float* dst = target + blockIdx.x * FD;
    #pragma unroll
    for (int u = 0; u < 5; u++) {
        float dx = (df[u] - dot * frv[u]) * invn;
        dst[t + 128 * u] -= LRDNI * dx;
    }
}

extern "C" void kernel_launch(void* const* d_in, const int* in_sizes, int n_in,
                              void* d_out, int out_size, void* d_ws, size_t ws_size,
                              hipStream_t stream) {
    const float* fs    = (const float*)d_in[0];
    const float* fq    = (const float*)d_in[1];
    const float* scale = (const float*)d_in[2];
    const float* W[12];
    for (int i = 0; i < 12; i++) W[i] = (const float*)d_in[3 + i];
    // W[0..5] = ds_{W1,b1,W2,b2,W3,b3}; W[6..11] = dq_*

    float* base = (float*)d_ws;
    float* supp = base;                     // 3200
    float* qbuf = supp + 3200;              // 48000
    float* f    = qbuf + 48000;             // 51200
    float* nrm  = f + 51200;                // 96 (pad)
    float* S    = nrm + 96;                 // 6400
    int*   perm = (int*)(S + 6400);         // 6480 -> pad 6496
    float* P1   = (float*)(perm + 6496);    // KS1*80*4096 = 2621440
    float* P2   = P1 + (size_t)KS1 * 80 * HIDN;   // KS2*80*4096 = 5242880
    float* P3   = P2 + (size_t)KS2 * 80 * HIDN;   // KS3*80*512  = 1310720
    float* Gs   = P3 + (size_t)KS3 * 80 * NPAD;   // 6400
    ushort* Xb  = (ushort*)(Gs + 6400);     // 80*512
    ushort* H1b = Xb + 80 * KPAD;           // 80*4096
    ushort* H2b = H1b + 80 * HIDN;          // 80*4096
    ushort* W1b_ds = H2b + 80 * HIDN;       // 4096*512
    ushort* W1b_dq = W1b_ds + HIDN * KPAD;
    ushort* W3b_ds = W1b_dq + HIDN * KPAD;  // 512*4096
    ushort* W3b_dq = W3b_ds + NPAD * HIDN;
    ushort* W2b_ds = W3b_dq + NPAD * HIDN;  // 4096*4096
    ushort* W2b_dq = W2b_ds + (size_t)HIDN * HIDN;

    k_cvtW1<<<8192, 256, 0, stream>>>(W[0],  W1b_ds);
    k_cvtW1<<<8192, 256, 0, stream>>>(W[6],  W1b_dq);
    k_cvtW3<<<8192, 256, 0, stream>>>(W[4],  W3b_ds);
    k_cvtW3<<<8192, 256, 0, stream>>>(W[10], W3b_dq);
    k_cvtW2<<<16384, 256, 0, stream>>>(W[2], W2b_ds);
    k_cvtW2<<<16384, 256, 0, stream>>>(W[8], W2b_dq);
    k_init<<<188, 256, 0, stream>>>(fs, fq, supp, qbuf);

    for (int step = 0; step < 3; step++) {
        for (int half = 0; half < 2; half++) {
            const float* const* w = (half == 0) ? W : (W + 6);
            const ushort* W1b = (half == 0) ? W1b_ds : W1b_dq;
            const ushort* W2b = (half == 0) ? W2b_ds : W2b_dq;
            const ushort* W3b = (half == 0) ? W3b_ds : W3b_dq;
            k_simrank<false><<<80, 128, 0, stream>>>(supp, qbuf, f, nrm, S, perm, nullptr, nullptr);
            k_gather<<<80, 512, 0, stream>>>(S, perm, Xb, Gs);
            // L1: M=80 N=4096 K=512; NT=1 (64 cols/block), KS1 splits, 2 ksteps
            k_gemm<1, 2><<<dim3(64, KS1), 256, 0, stream>>>(Xb, KPAD, W1b, KPAD, P1, HIDN);
            k_ep<KS1><<<320, 256, 0, stream>>>(P1, w[1], H1b);
            // L2: M=80 N=4096 K=4096; NT=2 (128 cols/block), KS2 splits, 8 ksteps
            k_gemm<2, 8><<<dim3(32, KS2), 256, 0, stream>>>(H1b, HIDN, W2b, HIDN, P2, HIDN);
            k_ep<KS2><<<320, 256, 0, stream>>>(P2, w[3], H2b);
            // L3: M=80 N=512 K=4096; NT=1, KS3 splits, 4 ksteps
            k_gemm<1, 4><<<dim3(8, KS3), 256, 0, stream>>>(H2b, HIDN, W3b, HIDN, P3, NPAD);
            k_scatter<<<80, 512, 0, stream>>>(P3, w[5], perm, Gs);
            if (half == 0) k_bwd<<<5, 128, 0, stream>>>(Gs, f, nrm, supp, 0);
            else           k_bwd<<<75, 128, 0, stream>>>(Gs, f, nrm, qbuf, NCLS);
        }
    }
    k_simrank<true><<<5, 128, 0, stream>>>(supp, qbuf, f, nrm, S, perm, scale, (float*)d_out);
}

// Round 5
// 632.999 us; speedup vs baseline: 1.0410x; 1.0410x over previous
//
#include <hip/hip_runtime.h>

#define NCLS 5
#define NQRY 75
#define NTOT 80            // N = 80
#define FD   640
#define HIDN 4096
#define DNIN 465
#define KPAD 512           // DNIN padded to 512 for MFMA K
#define NPAD 512           // DNIN padded for GEMM3 N
#define LRDNI 1e-3f

#define KS1 4              // K-splits layer1 (K=512  -> 4 ksteps)
#define KS2 16             // K-splits layer2 (K=4096 -> 8 ksteps)
#define KS3 32             // K-splits layer3 (K=4096 -> 4 ksteps)

typedef short  v8s __attribute__((ext_vector_type(8)));
typedef float  v4f __attribute__((ext_vector_type(4)));

__device__ __forceinline__ ushort f2bf(float x) {
    uint u = __float_as_uint(x);
    u = (u + 0x7FFFu + ((u >> 16) & 1u)) >> 16;
    return (ushort)u;
}
__device__ __forceinline__ uint pk2(float a, float b) {
    return (uint)f2bf(a) | ((uint)f2bf(b) << 16);
}

// ================= setup: all weight converts (frag-major) + init ===============
// Fragment-major layout: B'[ntile][kstep][lane][8] where element (n,k) lives at
// ntile=n>>4, kstep=k>>5, lane=((k>>3)&3)*16+(n&15), j=k&7.  A GEMM wave's
// 16B/lane fragment load is then 64 lanes x 16B CONTIGUOUS (one 1KB segment).
__global__ void k_setup(const float* __restrict__ fs, const float* __restrict__ fq,
                        const float* __restrict__ W1s, const float* __restrict__ W1q,
                        const float* __restrict__ W2s, const float* __restrict__ W2q,
                        const float* __restrict__ W3s, const float* __restrict__ W3q,
                        ushort* __restrict__ W1bs, ushort* __restrict__ W1bq,
                        ushort* __restrict__ W2bs, ushort* __restrict__ W2bq,
                        ushort* __restrict__ W3bs, ushort* __restrict__ W3bq,
                        float* __restrict__ supp, float* __restrict__ qbuf) {
    int stride = gridDim.x * 256;
    int tid = blockIdx.x * 256 + threadIdx.x;
    // --- W1 [4096][465] -> frag [256][16][64][8], 262144 octs each ---
    for (int o = tid; o < 524288; o += stride) {
        int oo = o & 262143;
        const float* Ws = (o < 262144) ? W1s : W1q;
        ushort* Wd = (o < 262144) ? W1bs : W1bq;
        int l = oo & 63, ks = (oo >> 6) & 15, nt = oo >> 10;
        int n = nt * 16 + (l & 15), kb = ks * 32 + ((l >> 4) << 3);
        ushort tmp[8];
        #pragma unroll
        for (int j = 0; j < 8; j++) {
            int k = kb + j;
            tmp[j] = (k < DNIN) ? f2bf(Ws[n * DNIN + k]) : (ushort)0;
        }
        *(uint4*)(Wd + (size_t)oo * 8) = *(uint4*)tmp;
    }
    // --- W3 [465][4096] -> frag [32][128][64][8], 262144 octs each ---
    for (int o = tid; o < 524288; o += stride) {
        int oo = o & 262143;
        const float* Ws = (o < 262144) ? W3s : W3q;
        ushort* Wd = (o < 262144) ? W3bs : W3bq;
        int l = oo & 63, ks = (oo >> 6) & 127, nt = oo >> 13;
        int n = nt * 16 + (l & 15), kb = ks * 32 + ((l >> 4) << 3);
        uint4 q;
        if (n < DNIN) {
            float4 f0 = *(const float4*)(Ws + (size_t)n * HIDN + kb);
            float4 f1 = *(const float4*)(Ws + (size_t)n * HIDN + kb + 4);
            q.x = pk2(f0.x, f0.y); q.y = pk2(f0.z, f0.w);
            q.z = pk2(f1.x, f1.y); q.w = pk2(f1.z, f1.w);
        } else q = (uint4){0, 0, 0, 0};
        *(uint4*)(Wd + (size_t)oo * 8) = q;
    }
    // --- W2 [4096][4096] -> frag [256][128][64][8], 2097152 octs each ---
    for (int o = tid; o < 4194304; o += stride) {
        int oo = o & 2097151;
        const float* Ws = (o < 2097152) ? W2s : W2q;
        ushort* Wd = (o < 2097152) ? W2bs : W2bq;
        int l = oo & 63, ks = (oo >> 6) & 127, nt = oo >> 13;
        int n = nt * 16 + (l & 15), kb = ks * 32 + ((l >> 4) << 3);
        float4 f0 = *(const float4*)(Ws + (size_t)n * HIDN + kb);
        float4 f1 = *(const float4*)(Ws + (size_t)n * HIDN + kb + 4);
        uint4 q;
        q.x = pk2(f0.x, f0.y); q.y = pk2(f0.z, f0.w);
        q.z = pk2(f1.x, f1.y); q.w = pk2(f1.z, f1.w);
        *(uint4*)(Wd + (size_t)oo * 8) = q;
    }
    // --- init: supp = mean(fs, axis=1); qbuf = fq ---
    for (int o = tid; o < NCLS * FD; o += stride) {
        int c = o / FD, d = o % FD;
        float s = 0.f;
        #pragma unroll
        for (int t = 0; t < 5; t++) s += fs[(c * 5 + t) * FD + d];
        supp[o] = s * 0.2f;
    }
    for (int o = tid; o < NQRY * FD / 4; o += stride)
        ((float4*)qbuf)[o] = ((const float4*)fq)[o];
}

__device__ __forceinline__ const float* rowptr(const float* supp, const float* qbuf, int r) {
    return (r < NCLS) ? (supp + r * FD) : (qbuf + (r - NCLS) * FD);
}

// ---- fused: norms + S = fn@fn^T + f (normalized) + stable rank -> perm --------
// FIN variant: only writes out[j*5+i] = S[i][5+j]*scale  (grid = 5 blocks)
template<bool FIN>
__global__ void k_simrank(const float* __restrict__ supp, const float* __restrict__ qbuf,
                          float* __restrict__ f, float* __restrict__ nrm,
                          float* __restrict__ S, int* __restrict__ perm,
                          const float* __restrict__ scale, float* __restrict__ out) {
    __shared__ float fi[FD];
    __shared__ float row[NTOT];
    __shared__ float ssh[NTOT];
    int i = blockIdx.x;
    int t = threadIdx.x;                // 128
    const float* ri = rowptr(supp, qbuf, i);
    for (int u = t; u < FD; u += 128) fi[u] = ri[u];
    __syncthreads();
    float dot = 0.f;
    if (t < NTOT) {
        const float* rj = rowptr(supp, qbuf, t);
        float ss = 0.f;
        for (int k = 0; k < FD; k += 4) {
            float4 a = *(const float4*)(fi + k);
            float4 b = *(const float4*)(rj + k);
            dot += a.x * b.x + a.y * b.y + a.z * b.z + a.w * b.w;
            ss  += b.x * b.x + b.y * b.y + b.z * b.z + b.w * b.w;
        }
        ssh[t] = ss;
    }
    __syncthreads();
    float ni = fmaxf(sqrtf(ssh[i]), 1e-12f);
    float inv_i = 1.0f / ni;
    if (t < NTOT) {
        float nt = fmaxf(sqrtf(ssh[t]), 1e-12f);
        float val = dot * inv_i / nt;
        if (FIN) {
            if (t >= NCLS) out[(t - NCLS) * NCLS + i] = val * scale[0];
        } else {
            row[t] = val;
            S[i * NTOT + t] = val;
        }
    }
    if (FIN) return;
    __syncthreads();
    for (int u = t; u < FD; u += 128) f[i * FD + u] = fi[u] * inv_i;
    if (t == 0) { nrm[i] = ni; perm[i * 81] = i; }
    if (t < NCLS) {
        float v = row[t]; int rank = 0;
        for (int k = 0; k < NCLS; k++) {
            float w = row[k];
            if (w > v || (w == v && k < t)) rank++;
        }
        perm[i * 81 + 1 + rank] = t;
    } else if (t < NTOT) {
        int j = t - NCLS; float v = row[t]; int rank = 0;
        for (int k = NCLS; k < NTOT; k++) {
            float w = row[k];
            if (w > v || (w == v && (k - NCLS) < j)) rank++;
        }
        perm[i * 81 + 6 + rank] = t;
    }
}

// m -> (a,b): masked entries of 81x81, row-major; a in 0..5, b in a+1..80
__device__ __forceinline__ void mask_ab(int m, int& a, int& b) {
    int start = 0, len = 80, aa = 0;
    while (m >= start + len) { start += len; len--; aa++; }
    a = aa; b = aa + 1 + (m - start);
}

// ---------------- gather Xb[i][m] = bf16(S[p[a]][p[b]]) + zero Gs ----------------
__global__ void k_gather(const float* __restrict__ S, const int* __restrict__ perm,
                         ushort* __restrict__ Xb, float* __restrict__ Gs) {
    __shared__ int p[81];
    int i = blockIdx.x;
    int t = threadIdx.x;                // 512
    if (t < 81) p[t] = perm[i * 81 + t];
    if (t < NTOT) Gs[i * NTOT + t] = 0.f;
    __syncthreads();
    if (t < DNIN) {
        int a, b; mask_ab(t, a, b);
        Xb[i * KPAD + t] = f2bf(S[p[a] * NTOT + p[b]]);
    } else if (t < KPAD) {
        Xb[i * KPAD + t] = 0;
    }
}

// ------- barrier-free MFMA GEMM partials, frag-major B ---------------------------
// P[ks][80][ldc] = A[80,K] @ B[N,K]^T for this block's K-split.
// A row-major bf16; B in fragment-major layout (see k_setup) -> every B load is
// a contiguous 1KB wave segment. No LDS, no syncthreads.
// NT = 16-col tiles per wave; block = 4 waves side by side. nks = Ktot/32.
template<int NT, int KSTEPS>
__global__ __launch_bounds__(256) void k_gemm(
        const ushort* __restrict__ A, int lda,
        const ushort* __restrict__ Bf, int nks,
        float* __restrict__ C, int ldc) {
    int tid = threadIdx.x;
    int w = tid >> 6, lane = tid & 63, l16 = lane & 15, quad = lane >> 4;
    int n0 = blockIdx.x * (NT * 64) + w * NT * 16;
    int kc0 = blockIdx.y * (KSTEPS * 32);
    const ushort* Ap = A + l16 * lda + kc0 + quad * 8;
    const ushort* Bp = Bf + ((size_t)(n0 >> 4) * nks + (kc0 >> 5)) * 512 + lane * 8;

    v4f acc[5][NT];
    #pragma unroll
    for (int mt = 0; mt < 5; mt++)
        #pragma unroll
        for (int nt = 0; nt < NT; nt++) acc[mt][nt] = (v4f){0.f, 0.f, 0.f, 0.f};

    #pragma unroll
    for (int s = 0; s < KSTEPS; s++) {
        v8s a[5], b[NT];
        #pragma unroll
        for (int mt = 0; mt < 5; mt++)
            a[mt] = *(const v8s*)(Ap + mt * 16 * lda + s * 32);
        #pragma unroll
        for (int nt = 0; nt < NT; nt++)
            b[nt] = *(const v8s*)(Bp + ((size_t)nt * nks + s) * 512);
        #pragma unroll
        for (int mt = 0; mt < 5; mt++)
            #pragma unroll
            for (int nt = 0; nt < NT; nt++)
                acc[mt][nt] = __builtin_amdgcn_mfma_f32_16x16x32_bf16(a[mt], b[nt], acc[mt][nt], 0, 0, 0);
    }
    // write fp32 partials: row = mt*16 + quad*4 + r ; col = n0 + nt*16 + l16
    float* Cp = C + (size_t)blockIdx.y * 80 * ldc;
    #pragma unroll
    for (int nt = 0; nt < NT; nt++) {
        int col = n0 + nt * 16 + l16;
        #pragma unroll
        for (int mt = 0; mt < 5; mt++)
            #pragma unroll
            for (int r = 0; r < 4; r++)
                Cp[(mt * 16 + quad * 4 + r) * ldc + col] = acc[mt][nt][r];
    }
}

// ---------------- H = bf16(relu(sum_ks P + bias))  (80 x 4096, x4 vectorized) ----
template<int NS>
__global__ void k_ep(const float* __restrict__ P, const float* __restrict__ bias,
                     ushort* __restrict__ H) {
    int idx = blockIdx.x * 256 + threadIdx.x;      // 80*4096/4
    float4 s = ((const float4*)bias)[idx & 1023];
    #pragma unroll
    for (int ks = 0; ks < NS; ks++) {
        float4 p = ((const float4*)P)[ks * (80 * HIDN / 4) + idx];
        s.x += p.x; s.y += p.y; s.z += p.z; s.w += p.w;
    }
    uint2 q;
    q.x = pk2(fmaxf(s.x, 0.f), fmaxf(s.y, 0.f));
    q.y = pk2(fmaxf(s.z, 0.f), fmaxf(s.w, 0.f));
    ((uint2*)H)[idx] = q;
}

// ---------------- scatter-add VJP of the gather (sums P3 partials + b3) --------
__global__ void k_scatter(const float* __restrict__ P3, const float* __restrict__ b3,
                          const int* __restrict__ perm, float* __restrict__ Gs) {
    __shared__ int p[81];
    int i = blockIdx.x;
    int t = threadIdx.x;                // 512
    if (t < 81) p[t] = perm[i * 81 + t];
    __syncthreads();
    if (t < DNIN) {
        float g = b3[t];
        #pragma unroll
        for (int ks = 0; ks < KS3; ks++) g += P3[ks * (80 * NPAD) + i * NPAD + t];
        int a, b; mask_ab(t, a, b);
        atomicAdd(&Gs[p[a] * NTOT + p[b]], g);
    }
}

// ---- dfeat = (Gs+Gs^T) @ f ; dx = (dfeat - (dfeat.f) f)/n ; target -= LR*dx ----
__global__ void k_bwd(const float* __restrict__ Gs, const float* __restrict__ f,
                      const float* __restrict__ nrm, float* __restrict__ target,
                      int row0) {
    int r = row0 + blockIdx.x;
    __shared__ float cj[NTOT];
    __shared__ float red[2];
    int t = threadIdx.x;                // 128 threads, 5 elems each
    if (t < NTOT) cj[t] = Gs[r * NTOT + t] + Gs[t * NTOT + r];
    __syncthreads();
    float df[5] = {0.f, 0.f, 0.f, 0.f, 0.f};
    for (int j = 0; j < NTOT; j++) {
        float c = cj[j];
        const float* fj = f + j * FD;
        #pragma unroll
        for (int u = 0; u < 5; u++) df[u] += c * fj[t + 128 * u];
    }
    const float* fr = f + r * FD;
    float frv[5]; float partial = 0.f;
    #pragma unroll
    for (int u = 0; u < 5; u++) { frv[u] = fr[t + 128 * u]; partial += df[u] * frv[u]; }
    #pragma unroll
    for (int o = 32; o > 0; o >>= 1) partial += __shfl_xor(partial, o, 64);
    if ((t & 63) == 0) red[t >> 6] = partial;
    __syncthreads();
    float dot = red[0] + red[1];
    float invn = 1.0f / nrm[r];
    float* dst = target + blockIdx.x * FD;
    #pragma unroll
    for (int u = 0; u < 5; u++) {
        float dx = (df[u] - dot * frv[u]) * invn;
        dst[t + 128 * u] -= LRDNI * dx;
    }
}

extern "C" void kernel_launch(void* const* d_in, const int* in_sizes, int n_in,
                              void* d_out, int out_size, void* d_ws, size_t ws_size,
                              hipStream_t stream) {
    const float* fs    = (const float*)d_in[0];
    const float* fq    = (const float*)d_in[1];
    const float* scale = (const float*)d_in[2];
    const float* W[12];
    for (int i = 0; i < 12; i++) W[i] = (const float*)d_in[3 + i];
    // W[0..5] = ds_{W1,b1,W2,b2,W3,b3}; W[6..11] = dq_*

    float* base = (float*)d_ws;
    float* supp = base;                     // 3200
    float* qbuf = supp + 3200;              // 48000
    float* f    = qbuf + 48000;             // 51200
    float* nrm  = f + 51200;                // 96 (pad)
    float* S    = nrm + 96;                 // 6400
    int*   perm = (int*)(S + 6400);         // 6480 -> pad 6496
    float* P1   = (float*)(perm + 6496);    // KS1*80*4096 = 1310720
    float* P2   = P1 + (size_t)KS1 * 80 * HIDN;   // KS2*80*4096 = 5242880
    float* P3   = P2 + (size_t)KS2 * 80 * HIDN;   // KS3*80*512  = 1310720
    float* Gs   = P3 + (size_t)KS3 * 80 * NPAD;   // 6400
    ushort* Xb  = (ushort*)(Gs + 6400);     // 80*512
    ushort* H1b = Xb + 80 * KPAD;           // 80*4096
    ushort* H2b = H1b + 80 * HIDN;          // 80*4096
    ushort* W1b_ds = H2b + 80 * HIDN;       // 4096*512 (frag-major)
    ushort* W1b_dq = W1b_ds + HIDN * KPAD;
    ushort* W3b_ds = W1b_dq + HIDN * KPAD;  // 512*4096 (frag-major)
    ushort* W3b_dq = W3b_ds + NPAD * HIDN;
    ushort* W2b_ds = W3b_dq + NPAD * HIDN;  // 4096*4096 (frag-major)
    ushort* W2b_dq = W2b_ds + (size_t)HIDN * HIDN;

    k_setup<<<1024, 256, 0, stream>>>(fs, fq, W[0], W[6], W[2], W[8], W[4], W[10],
                                      W1b_ds, W1b_dq, W2b_ds, W2b_dq, W3b_ds, W3b_dq,
                                      supp, qbuf);

    for (int step = 0; step < 3; step++) {
        for (int half = 0; half < 2; half++) {
            const float* const* w = (half == 0) ? W : (W + 6);
            const ushort* W1b = (half == 0) ? W1b_ds : W1b_dq;
            const ushort* W2b = (half == 0) ? W2b_ds : W2b_dq;
            const ushort* W3b = (half == 0) ? W3b_ds : W3b_dq;
            k_simrank<false><<<80, 128, 0, stream>>>(supp, qbuf, f, nrm, S, perm, nullptr, nullptr);
            k_gather<<<80, 512, 0, stream>>>(S, perm, Xb, Gs);
            // L1: M=80 N=4096 K=512; NT=1, KS1 splits, 4 ksteps, nks=16
            k_gemm<1, 4><<<dim3(64, KS1), 256, 0, stream>>>(Xb, KPAD, W1b, 16, P1, HIDN);
            k_ep<KS1><<<320, 256, 0, stream>>>(P1, w[1], H1b);
            // L2: M=80 N=4096 K=4096; NT=2, KS2 splits, 8 ksteps, nks=128
            k_gemm<2, 8><<<dim3(32, KS2), 256, 0, stream>>>(H1b, HIDN, W2b, 128, P2, HIDN);
            k_ep<KS2><<<320, 256, 0, stream>>>(P2, w[3], H2b);
            // L3: M=80 N=512 K=4096; NT=1, KS3 splits, 4 ksteps, nks=128
            k_gemm<1, 4><<<dim3(8, KS3), 256, 0, stream>>>(H2b, HIDN, W3b, 128, P3, NPAD);
            k_scatter<<<80, 512, 0, stream>>>(P3, w[5], perm, Gs);
            if (half == 0) k_bwd<<<5, 128, 0, stream>>>(Gs, f, nrm, supp, 0);
            else           k_bwd<<<75, 128, 0, stream>>>(Gs, f, nrm, qbuf, NCLS);
        }
    }
    k_simrank<true><<<5, 128, 0, stream>>>(supp, qbuf, f, nrm, S, perm, scale, (float*)d_out);
}